// Round 11
// baseline (367.161 us; speedup 1.0000x reference)
//
#include <hip/hip_runtime.h>
#include <hip/hip_bf16.h>
#include <hip/hip_cooperative_groups.h>

namespace cg = cooperative_groups;

// Problem constants
constexpr int L   = 32768;   // 32*32*32 sequence length
constexpr int CD  = 32;      // d_model
constexpr int DI  = 64;      // d_inner
constexpr int DS  = 16;      // d_state
constexpr int LC  = 64;      // chunk length (= block ownership, fused path)
constexpr int NCH = L / LC;  // 512 chunks = fused grid size
constexpr int LH  = 32;      // fallback k45 half-chunk length
constexpr int NHC = L / LH;  // 1024 half-chunks (fallback)
constexpr int NPAIR = DI * DS; // 1024 (d,s) pairs

// ---- Fused-path workspace (float offsets) ----
constexpr size_t CO_SZ    = 0;         // bf16 [DI][L] silu(z)   (1M floats)
constexpr size_t CO_APROD = 1048576;   // [NCH][NPAIR] prod(a)   (0.5M)
constexpr size_t CO_BACC  = 1572864;   // [NCH][NPAIR] b_end     (0.5M)
constexpr size_t CO_CARRY = 2097152;   // [NCH][NPAIR] carry     (0.5M)

// ---- Fallback-path workspace (R9 layout) ----
constexpr size_t OFF_SZ    = 0;        // bf16 [DI][L]
constexpr size_t OFF_XC    = 1048576;  // bf16 [DI][L]
constexpr size_t OFF_DELTA = 2097152;  // fp32 [DI][L]
constexpr size_t OFF_BM    = 4194304;  // fp32 [DS][L]
constexpr size_t OFF_CM    = 4718592;  // fp32 [DS][L]
constexpr size_t OFF_APROD = 5242880;  // [NHC][NPAIR]
constexpr size_t OFF_BACC  = 6291456;  // [NHC][NPAIR]
constexpr size_t OFF_CT    = 7340032;  // [NHC][NPAIR]

__device__ __forceinline__ float bf2f(__hip_bfloat16 v) { return __bfloat162float(v); }
__device__ __forceinline__ float bfu(unsigned short u) { return __uint_as_float(((unsigned)u) << 16); }
__device__ __forceinline__ unsigned short f2bu(float f) { __hip_bfloat16 h = __float2bfloat16(f); return *(unsigned short*)&h; }
__device__ __forceinline__ void f4arr(const float4 v, float* a) { a[0]=v.x; a[1]=v.y; a[2]=v.z; a[3]=v.w; }

__device__ __forceinline__ bool detect_bf16(const void* ln_w) {
    return ((const unsigned short*)ln_w)[0] == 0x3F80;
}
__device__ __forceinline__ float ldin(const void* p, size_t i, bool bf16) {
    return bf16 ? bf2f(((const __hip_bfloat16*)p)[i]) : ((const float*)p)[i];
}

// ===========================================================================
// FUSED cooperative kernel. 512 blocks x 256 threads, LDS 64,784 B (<64 KiB
// so every occupancy model gives >=2 blocks/CU -> co-residency holds).
// Intermediates delta/xc/Bm/Cm live only in LDS; silu(z) round-trips global
// as bf16. Two grid.sync()s bracket the carry scan.
// ===========================================================================
__global__ __launch_bounds__(256, 2) void fused_umamba(
    const void* __restrict__ x,
    const void* __restrict__ ln_w,
    const void* __restrict__ ln_b,
    const void* __restrict__ in_proj_w,  // [128][32]
    const void* __restrict__ conv_w,     // [64][1][4]
    const void* __restrict__ conv_b,     // [64]
    const void* __restrict__ x_proj_w,   // [34][64]
    const void* __restrict__ dt_proj_w,  // [64][2]
    const void* __restrict__ dt_proj_b,  // [64]
    const void* __restrict__ A_log,      // [64][16]
    const void* __restrict__ D_param,    // [64]
    const void* __restrict__ out_proj_w, // [32][64]
    float* __restrict__ ws,
    void* __restrict__ out)
{
    __shared__ __align__(16) char smem[64784];
    float (*xin_s)[69]   = (float(*)[69])(smem);                 // [64][69] 17,664
    float (*w_out_s)[DI] = (float(*)[DI])(smem);                 // alias (epilogue)
    char* AR = smem + 17664;                                     // 25,232 B
    float (*xn_s)[33]    = (float(*)[33])(AR);                   // phase A
    float (*w_in_s)[32]  = (float(*)[32])(AR + 8848);            // phase A
    float (*sdl)[68]     = (float(*)[68])(AR);                   // B..apply; sy alias
    float (*scm)[68]     = (float(*)[68])(AR + 17408);           // B..apply
    unsigned short (*sxc)[68] = (unsigned short(*)[68])(smem + 42896); // 8,704
    unsigned short (*sbm)[68] = (unsigned short(*)[68])(smem + 51600); // 2,176 (bf16)
    float (*w_xp)[64]    = (float(*)[64])(smem + 53776);         // 8,704
    float (*aggA)[17]    = (float(*)[17])(smem + 53776);         // carry alias
    float (*aggB)[17]    = (float(*)[17])(smem + 54864);
    float (*w_cv)[4]     = (float(*)[4])(smem + 62480);
    float (*w_dt)[2]     = (float(*)[2])(smem + 63504);
    float* b_dt_s = (float*)(smem + 64016);
    float* b_cv_s = (float*)(smem + 64272);
    float* lnw_s  = (float*)(smem + 64528);
    float* lnb_s  = (float*)(smem + 64656);                      // end 64,784

    const int tid = threadIdx.x;
    const int bid = blockIdx.x;
    const int l0  = bid * LC;
    const bool isb = detect_bf16(ln_w);
    __hip_bfloat16* sz_bf = (__hip_bfloat16*)(ws + CO_SZ);
    cg::grid_group grid = cg::this_grid();

    // ---- stage weights ----
    if (isb) {
        const __hip_bfloat16* ipw = (const __hip_bfloat16*)in_proj_w;
        const __hip_bfloat16* xpw = (const __hip_bfloat16*)x_proj_w;
        for (int i = tid; i < 128 * 32; i += 256) w_in_s[i >> 5][i & 31] = bf2f(ipw[i]);
        for (int i = tid; i < 34 * 64; i += 256)  w_xp[i >> 6][i & 63] = bf2f(xpw[i]);
    } else {
        const float* ipw = (const float*)in_proj_w;
        const float* xpw = (const float*)x_proj_w;
        for (int i = tid; i < 128 * 32; i += 256) w_in_s[i >> 5][i & 31] = ipw[i];
        for (int i = tid; i < 34 * 64; i += 256)  w_xp[i >> 6][i & 63] = xpw[i];
    }
    w_cv[tid >> 2][tid & 3] = ldin(conv_w, tid, isb);
    if (tid < 128) w_dt[tid >> 1][tid & 1] = ldin(dt_proj_w, tid, isb);
    if (tid < 64) { b_dt_s[tid] = ldin(dt_proj_b, tid, isb); b_cv_s[tid] = ldin(conv_b, tid, isb); }
    if (tid < 32) { lnw_s[tid] = ldin(ln_w, tid, isb); lnb_s[tid] = ldin(ln_b, tid, isb); }
    const int d = tid >> 2, sg = tid & 3;
    float Aj[4];
    #pragma unroll
    for (int j = 0; j < 4; ++j) Aj[j] = -__expf(ldin(A_log, d * DS + sg + 4 * j, isb));
    const float Dd = ldin(D_param, d, isb);
    __syncthreads();

    // ---- LN once per position -> xn_s ----
    if (tid < LC + 3) {
        const int l = l0 - 3 + tid;
        const bool valid = (l >= 0);
        const int lc = valid ? l : 0;
        float xv[CD];
        if (isb) {
            const __hip_bfloat16* xb = (const __hip_bfloat16*)x;
            #pragma unroll
            for (int c = 0; c < CD; ++c) xv[c] = bf2f(xb[(size_t)c * L + lc]);
        } else {
            const float* xf = (const float*)x;
            #pragma unroll
            for (int c = 0; c < CD; ++c) xv[c] = xf[(size_t)c * L + lc];
        }
        float mu = 0.f;
        #pragma unroll
        for (int c = 0; c < CD; ++c) mu += xv[c];
        mu *= (1.f / CD);
        float var = 0.f;
        #pragma unroll
        for (int c = 0; c < CD; ++c) { const float dc = xv[c] - mu; var += dc * dc; }
        const float rstd = rsqrtf(var * (1.f / CD) + 1e-5f);
        #pragma unroll
        for (int c = 0; c < CD; ++c)
            xn_s[tid][c] = valid ? ((xv[c] - mu) * rstd * lnw_s[c] + lnb_s[c]) : 0.f;
    }
    __syncthreads();

    // ---- in_proj GEMM: wave-uniform j, LDS-broadcast weights ----
    {
        const int wv   = tid >> 6;
        const int lane = tid & 63;
        const int jb   = wv * 32;
        if (wv < 2) {
            const int pos1  = 64 + lane;
            const bool v1   = (pos1 < LC + 3);
            const int pos1c = v1 ? pos1 : 66;
            float xv0[CD], xv1[CD];
            #pragma unroll
            for (int c = 0; c < CD; ++c) { xv0[c] = xn_s[lane][c]; xv1[c] = xn_s[pos1c][c]; }
            for (int j = 0; j < 32; ++j) {
                const float4* wr = (const float4*)w_in_s[jb + j];
                float a0 = 0.f, a1 = 0.f;
                #pragma unroll
                for (int q = 0; q < 8; ++q) {
                    const float4 w4 = wr[q];
                    a0 += w4.x * xv0[4*q] + w4.y * xv0[4*q+1] + w4.z * xv0[4*q+2] + w4.w * xv0[4*q+3];
                    a1 += w4.x * xv1[4*q] + w4.y * xv1[4*q+1] + w4.z * xv1[4*q+2] + w4.w * xv1[4*q+3];
                }
                xin_s[jb + j][lane] = a0;
                if (v1) xin_s[jb + j][pos1] = a1;
            }
        } else {
            const int l = l0 + lane;
            float xv[CD];
            #pragma unroll
            for (int c = 0; c < CD; ++c) xv[c] = xn_s[3 + lane][c];
            for (int j = 0; j < 32; ++j) {
                const float4* wr = (const float4*)w_in_s[jb + j];
                float acc = 0.f;
                #pragma unroll
                for (int q = 0; q < 8; ++q) {
                    const float4 w4 = wr[q];
                    acc += w4.x * xv[4*q] + w4.y * xv[4*q+1] + w4.z * xv[4*q+2] + w4.w * xv[4*q+3];
                }
                const float s = acc / (1.f + __expf(-acc)); // silu(z)
                sz_bf[(size_t)(jb - 64 + j) * L + l] = __float2bfloat16(s);
            }
        }
    }
    __syncthreads();   // xn/w_in dead -> sdl/scm live

    // ---- Phase B: conv+silu -> sxc; x_proj -> sbm/scm; dt -> sdl ----
    {
        const int h  = tid & 3;
        const int pq = tid >> 2;
        const int dbase = h * 16;
        float xcv[16];
        #pragma unroll
        for (int i = 0; i < 16; ++i) {
            const int dd = dbase + i;
            float acc = b_cv_s[dd];
            #pragma unroll
            for (int k = 0; k < 4; ++k) acc += w_cv[dd][k] * xin_s[dd][pq + k];
            const float v = acc / (1.f + __expf(-acc)); // silu
            xcv[i] = v;
            sxc[dd][pq] = f2bu(v);
        }
        float dt0 = 0.f, dt1 = 0.f;
        for (int r = 0; r < 34; ++r) {
            float acc = 0.f;
            #pragma unroll
            for (int i = 0; i < 16; ++i) acc += w_xp[r][dbase + i] * xcv[i];
            acc += __shfl_xor(acc, 1);
            acc += __shfl_xor(acc, 2);
            if (r == 0) dt0 = acc;
            else if (r == 1) dt1 = acc;
            else {
                const int rr = r - 2;
                if (h == (rr >> 3)) {
                    if (rr < 16) sbm[rr][pq] = f2bu(acc);
                    else         scm[rr - 16][pq] = acc;
                }
            }
        }
        #pragma unroll
        for (int i = 0; i < 16; ++i) {
            const int dd = dbase + i;
            const float tv = dt0 * w_dt[dd][0] + dt1 * w_dt[dd][1] + b_dt_s[dd];
            const float sp = fmaxf(tv, 0.f) + log1pf(__expf(-fabsf(tv))); // softplus
            sdl[dd][pq] = sp;
        }
    }
    __syncthreads();

    // ---- Phase C: full-chunk scan summaries -> global (coalesced f4 rows) ----
    {
        float ap[4] = {1.f, 1.f, 1.f, 1.f}, bb[4] = {0.f, 0.f, 0.f, 0.f};
        for (int t = 0; t < LC; t += 4) {
            float ddv[4], xxv[4], bm[4][4];
            f4arr(*(const float4*)&sdl[d][t], ddv);
            const ushort4 xq = *(const ushort4*)&sxc[d][t];
            xxv[0] = bfu(xq.x); xxv[1] = bfu(xq.y); xxv[2] = bfu(xq.z); xxv[3] = bfu(xq.w);
            #pragma unroll
            for (int j = 0; j < 4; ++j) {
                const ushort4 bq = *(const ushort4*)&sbm[sg + 4 * j][t];
                bm[j][0] = bfu(bq.x); bm[j][1] = bfu(bq.y); bm[j][2] = bfu(bq.z); bm[j][3] = bfu(bq.w);
            }
            #pragma unroll
            for (int tt = 0; tt < 4; ++tt) {
                const float dxc = ddv[tt] * xxv[tt];
                #pragma unroll
                for (int j = 0; j < 4; ++j) {
                    const float e = __expf(ddv[tt] * Aj[j]);
                    ap[j] *= e;
                    bb[j] = e * bb[j] + dxc * bm[j][tt];
                }
            }
        }
        const size_t o = (size_t)bid * NPAIR + tid * 4;
        *(float4*)&ws[CO_APROD + o] = make_float4(ap[0], ap[1], ap[2], ap[3]);
        *(float4*)&ws[CO_BACC + o]  = make_float4(bb[0], bb[1], bb[2], bb[3]);
    }
    __threadfence();
    grid.sync();

    // ---- Carry scan (blocks 0-63): 16 pairs x 16 groups of 32 chunks ----
    if (bid < 64) {
        const int pl = tid & 15;
        const int g  = tid >> 4;
        const int p  = bid * 16 + pl;
        float a[32], b[32];
        #pragma unroll 8
        for (int i = 0; i < 32; ++i) {
            const size_t c = (size_t)(g * 32 + i);
            a[i] = ws[CO_APROD + c * NPAIR + p];
            b[i] = ws[CO_BACC  + c * NPAIR + p];
        }
        float Ag = a[0], Bg = b[0];
        #pragma unroll 8
        for (int i = 1; i < 32; ++i) { Bg = a[i] * Bg + b[i]; Ag = Ag * a[i]; }
        aggA[g][pl] = Ag;
        aggB[g][pl] = Bg;
        __syncthreads();
        if (tid < 16) {
            float Pb = 0.f;
            for (int gg = 0; gg < 16; ++gg) {
                const float ta = aggA[gg][tid];
                const float tb = aggB[gg][tid];
                aggB[gg][tid] = Pb;
                Pb = ta * Pb + tb;
            }
        }
        __syncthreads();
        float Pb = aggB[g][pl];
        #pragma unroll 8
        for (int i = 0; i < 32; ++i) {
            const size_t c = (size_t)(g * 32 + i);
            ws[CO_CARRY + c * NPAIR + p] = Pb;
            Pb = a[i] * Pb + b[i];
        }
    }
    // all blocks: stage out_proj into (dead) xin region
    if (isb) {
        const __hip_bfloat16* opw = (const __hip_bfloat16*)out_proj_w;
        for (int i = tid; i < CD * DI; i += 256) w_out_s[i >> 6][i & 63] = bf2f(opw[i]);
    } else {
        const float* opw = (const float*)out_proj_w;
        for (int i = tid; i < CD * DI; i += 256) w_out_s[i >> 6][i & 63] = opw[i];
    }
    __threadfence();
    grid.sync();

    // ---- Apply scan (LDS; sy aliases sdl -- same-wave read-before-write) ----
    {
        const float4 h4 = *(const float4*)&ws[CO_CARRY + (size_t)bid * NPAIR + tid * 4];
        float hh[4]; f4arr(h4, hh);
        float (*sy)[68] = sdl;
        for (int t = 0; t < LC; t += 4) {
            float ddv[4], xxv[4], bm[4][4], cm[4][4];
            f4arr(*(const float4*)&sdl[d][t], ddv);
            const ushort4 xq = *(const ushort4*)&sxc[d][t];
            xxv[0] = bfu(xq.x); xxv[1] = bfu(xq.y); xxv[2] = bfu(xq.z); xxv[3] = bfu(xq.w);
            #pragma unroll
            for (int j = 0; j < 4; ++j) {
                const ushort4 bq = *(const ushort4*)&sbm[sg + 4 * j][t];
                bm[j][0] = bfu(bq.x); bm[j][1] = bfu(bq.y); bm[j][2] = bfu(bq.z); bm[j][3] = bfu(bq.w);
            }
            f4arr(*(const float4*)&scm[sg][t],      cm[0]);
            f4arr(*(const float4*)&scm[sg + 4][t],  cm[1]);
            f4arr(*(const float4*)&scm[sg + 8][t],  cm[2]);
            f4arr(*(const float4*)&scm[sg + 12][t], cm[3]);
            #pragma unroll
            for (int tt = 0; tt < 4; ++tt) {
                const float dxc = ddv[tt] * xxv[tt];
                float ys = 0.f;
                #pragma unroll
                for (int j = 0; j < 4; ++j) {
                    const float e = __expf(ddv[tt] * Aj[j]);
                    hh[j] = e * hh[j] + dxc * bm[j][tt];
                    ys += hh[j] * cm[j][tt];
                }
                ys += __shfl_xor(ys, 1);
                ys += __shfl_xor(ys, 2);
                if (sg == 0) sy[d][t + tt] = ys + xxv[tt] * Dd;
            }
        }
    }
    __syncthreads();

    // ---- gate: sy *= silu(z) (global bf16) ----
    {
        float (*sy)[68] = sdl;
        #pragma unroll
        for (int k = 0; k < 4; ++k) {
            const int idx = tid + k * 256;
            const int r = idx >> 4, c4 = (idx & 15) * 4;
            float4 yv = *(float4*)&sy[r][c4];
            const ushort4 zq = *(const ushort4*)(sz_bf + (size_t)r * L + l0 + c4);
            yv.x *= bfu(zq.x); yv.y *= bfu(zq.y); yv.z *= bfu(zq.z); yv.w *= bfu(zq.w);
            *(float4*)&sy[r][c4] = yv;
        }
    }
    __syncthreads();

    // ---- out_proj epilogue ----
    {
        float (*sy)[68] = sdl;
        const int wv   = tid >> 6;
        const int lane = tid & 63;
        float acc[8] = {0.f, 0.f, 0.f, 0.f, 0.f, 0.f, 0.f, 0.f};
        for (int dd = 0; dd < DI; ++dd) {
            const float yv = sy[dd][lane];
            #pragma unroll
            for (int j = 0; j < 8; ++j)
                acc[j] += yv * w_out_s[wv * 8 + j][dd];
        }
        const size_t l = (size_t)l0 + lane;
        #pragma unroll
        for (int j = 0; j < 8; ++j) {
            const int cc = wv * 8 + j;
            if (isb) ((__hip_bfloat16*)out)[(size_t)cc * L + l] = __float2bfloat16(acc[j]);
            else     ((float*)out)[(size_t)cc * L + l] = acc[j];
        }
    }
}

// ===========================================================================
// FALLBACK path (R9, known-passing): used only if cooperative launch fails.
// ===========================================================================
__global__ __launch_bounds__(256) void k12_featurize_scan(
    const void* __restrict__ x, const void* __restrict__ ln_w,
    const void* __restrict__ ln_b, const void* __restrict__ in_proj_w,
    const void* __restrict__ conv_w, const void* __restrict__ conv_b,
    const void* __restrict__ x_proj_w, const void* __restrict__ dt_proj_w,
    const void* __restrict__ dt_proj_b, const void* __restrict__ A_log,
    float* __restrict__ ws)
{
    __shared__ __align__(16) char smem[67840];
    float (*xin_s)[69]  = (float(*)[69])(smem);
    char* AR = smem + 17664;
    float (*xn_s)[33]   = (float(*)[33])(AR);
    float (*w_in_s)[32] = (float(*)[32])(AR + 8848);
    float (*sdl)[68]    = (float(*)[68])(AR);
    float (*sxc)[68]    = (float(*)[68])(AR + 17408);
    float (*sbm)[68]    = (float(*)[68])(AR + 34816);
    char* FW = smem + 56832;
    float (*w_xp)[64]   = (float(*)[64])(FW);
    float (*w_cv)[4]    = (float(*)[4])(FW + 8704);
    float (*w_dt)[2]    = (float(*)[2])(FW + 9728);
    float* b_dt_s = (float*)(FW + 10240);
    float* b_cv_s = (float*)(FW + 10496);
    float* lnw_s  = (float*)(FW + 10752);
    float* lnb_s  = (float*)(FW + 10880);

    const int tid = threadIdx.x;
    const int l0  = blockIdx.x * LC;
    const bool isb = detect_bf16(ln_w);
    __hip_bfloat16* sz_bf = (__hip_bfloat16*)(ws + OFF_SZ);
    __hip_bfloat16* xc_bf = (__hip_bfloat16*)(ws + OFF_XC);

    if (isb) {
        const __hip_bfloat16* ipw = (const __hip_bfloat16*)in_proj_w;
        const __hip_bfloat16* xpw = (const __hip_bfloat16*)x_proj_w;
        for (int i = tid; i < 128 * 32; i += 256) w_in_s[i >> 5][i & 31] = bf2f(ipw[i]);
        for (int i = tid; i < 34 * 64; i += 256)  w_xp[i >> 6][i & 63] = bf2f(xpw[i]);
    } else {
        const float* ipw = (const float*)in_proj_w;
        const float* xpw = (const float*)x_proj_w;
        for (int i = tid; i < 128 * 32; i += 256) w_in_s[i >> 5][i & 31] = ipw[i];
        for (int i = tid; i < 34 * 64; i += 256)  w_xp[i >> 6][i & 63] = xpw[i];
    }
    w_cv[tid >> 2][tid & 3] = ldin(conv_w, tid, isb);
    if (tid < 128) w_dt[tid >> 1][tid & 1] = ldin(dt_proj_w, tid, isb);
    if (tid < 64) { b_dt_s[tid] = ldin(dt_proj_b, tid, isb); b_cv_s[tid] = ldin(conv_b, tid, isb); }
    if (tid < 32) { lnw_s[tid] = ldin(ln_w, tid, isb); lnb_s[tid] = ldin(ln_b, tid, isb); }
    __syncthreads();

    if (tid < LC + 3) {
        const int l = l0 - 3 + tid;
        const bool valid = (l >= 0);
        const int lc = valid ? l : 0;
        float xv[CD];
        if (isb) {
            const __hip_bfloat16* xb = (const __hip_bfloat16*)x;
            #pragma unroll
            for (int c = 0; c < CD; ++c) xv[c] = bf2f(xb[(size_t)c * L + lc]);
        } else {
            const float* xf = (const float*)x;
            #pragma unroll
            for (int c = 0; c < CD; ++c) xv[c] = xf[(size_t)c * L + lc];
        }
        float mu = 0.f;
        #pragma unroll
        for (int c = 0; c < CD; ++c) mu += xv[c];
        mu *= (1.f / CD);
        float var = 0.f;
        #pragma unroll
        for (int c = 0; c < CD; ++c) { const float dc = xv[c] - mu; var += dc * dc; }
        const float rstd = rsqrtf(var * (1.f / CD) + 1e-5f);
        #pragma unroll
        for (int c = 0; c < CD; ++c)
            xn_s[tid][c] = valid ? ((xv[c] - mu) * rstd * lnw_s[c] + lnb_s[c]) : 0.f;
    }
    __syncthreads();

    {
        const int wv   = tid >> 6;
        const int lane = tid & 63;
        const int jb   = wv * 32;
        if (wv < 2) {
            const int pos1  = 64 + lane;
            const bool v1   = (pos1 < LC + 3);
            const int pos1c = v1 ? pos1 : 66;
            float xv0[CD], xv1[CD];
            #pragma unroll
            for (int c = 0; c < CD; ++c) { xv0[c] = xn_s[lane][c]; xv1[c] = xn_s[pos1c][c]; }
            for (int j = 0; j < 32; ++j) {
                const float4* wr = (const float4*)w_in_s[jb + j];
                float a0 = 0.f, a1 = 0.f;
                #pragma unroll
                for (int q = 0; q < 8; ++q) {
                    const float4 w4 = wr[q];
                    a0 += w4.x * xv0[4*q] + w4.y * xv0[4*q+1] + w4.z * xv0[4*q+2] + w4.w * xv0[4*q+3];
                    a1 += w4.x * xv1[4*q] + w4.y * xv1[4*q+1] + w4.z * xv1[4*q+2] + w4.w * xv1[4*q+3];
                }
                xin_s[jb + j][lane] = a0;
                if (v1) xin_s[jb + j][pos1] = a1;
            }
        } else {
            const int l = l0 + lane;
            float xv[CD];
            #pragma unroll
            for (int c = 0; c < CD; ++c) xv[c] = xn_s[3 + lane][c];
            for (int j = 0; j < 32; ++j) {
                const float4* wr = (const float4*)w_in_s[jb + j];
                float acc = 0.f;
                #pragma unroll
                for (int q = 0; q < 8; ++q) {
                    const float4 w4 = wr[q];
                    acc += w4.x * xv[4*q] + w4.y * xv[4*q+1] + w4.z * xv[4*q+2] + w4.w * xv[4*q+3];
                }
                const float s = acc / (1.f + __expf(-acc));
                sz_bf[(size_t)(jb - 64 + j) * L + l] = __float2bfloat16(s);
            }
        }
    }
    __syncthreads();

    {
        const int h  = tid & 3;
        const int pq = tid >> 2;
        const int l  = l0 + pq;
        const int dbase = h * 16;
        float xcv[16];
        #pragma unroll
        for (int i = 0; i < 16; ++i) {
            const int dd = dbase + i;
            float acc = b_cv_s[dd];
            #pragma unroll
            for (int k = 0; k < 4; ++k) acc += w_cv[dd][k] * xin_s[dd][pq + k];
            const float v = acc / (1.f + __expf(-acc));
            xcv[i] = v;
            xc_bf[(size_t)dd * L + l] = __float2bfloat16(v);
            sxc[dd][pq] = v;
        }
        float dt0 = 0.f, dt1 = 0.f;
        for (int r = 0; r < 34; ++r) {
            float acc = 0.f;
            #pragma unroll
            for (int i = 0; i < 16; ++i) acc += w_xp[r][dbase + i] * xcv[i];
            acc += __shfl_xor(acc, 1);
            acc += __shfl_xor(acc, 2);
            if (r == 0) dt0 = acc;
            else if (r == 1) dt1 = acc;
            else {
                const int rr = r - 2;
                if (h == (rr >> 3)) {
                    const size_t off = (rr < 16) ? (OFF_BM + (size_t)rr * L)
                                                 : (OFF_CM + (size_t)(rr - 16) * L);
                    ws[off + l] = acc;
                    if (rr < 16) sbm[rr][pq] = acc;
                }
            }
        }
        #pragma unroll
        for (int i = 0; i < 16; ++i) {
            const int dd = dbase + i;
            const float tv = dt0 * w_dt[dd][0] + dt1 * w_dt[dd][1] + b_dt_s[dd];
            const float sp = fmaxf(tv, 0.f) + log1pf(__expf(-fabsf(tv)));
            ws[OFF_DELTA + (size_t)dd * L + l] = sp;
            sdl[dd][pq] = sp;
        }
    }
    __syncthreads();

    {
        const int d = tid >> 2, sg = tid & 3;
        float Aj[4];
        #pragma unroll
        for (int j = 0; j < 4; ++j) Aj[j] = -__expf(ldin(A_log, d * DS + sg + 4 * j, isb));
        #pragma unroll
        for (int half = 0; half < 2; ++half) {
            float ap[4] = {1.f, 1.f, 1.f, 1.f}, bb[4] = {0.f, 0.f, 0.f, 0.f};
            for (int t = half * 32; t < half * 32 + 32; t += 4) {
                float ddv[4], xxv[4], bm[4][4];
                f4arr(*(const float4*)&sdl[d][t], ddv);
                f4arr(*(const float4*)&sxc[d][t], xxv);
                f4arr(*(const float4*)&sbm[sg][t],      bm[0]);
                f4arr(*(const float4*)&sbm[sg + 4][t],  bm[1]);
                f4arr(*(const float4*)&sbm[sg + 8][t],  bm[2]);
                f4arr(*(const float4*)&sbm[sg + 12][t], bm[3]);
                #pragma unroll
                for (int tt = 0; tt < 4; ++tt) {
                    const float dxc = ddv[tt] * xxv[tt];
                    #pragma unroll
                    for (int j = 0; j < 4; ++j) {
                        const float e = __expf(ddv[tt] * Aj[j]);
                        ap[j] *= e;
                        bb[j] = e * bb[j] + dxc * bm[j][tt];
                    }
                }
            }
            const size_t o = (size_t)(2 * blockIdx.x + half) * NPAIR + tid * 4;
            *(float4*)&ws[OFF_APROD + o] = make_float4(ap[0], ap[1], ap[2], ap[3]);
            *(float4*)&ws[OFF_BACC + o]  = make_float4(bb[0], bb[1], bb[2], bb[3]);
        }
    }
}

__global__ __launch_bounds__(1024) void k3_carry(float* __restrict__ ws)
{
    __shared__ float aggA[64][17];
    __shared__ float aggB[64][17];
    const int t  = threadIdx.x;
    const int pl = t & 15;
    const int g  = t >> 4;
    const int p  = blockIdx.x * 16 + pl;

    float a[16], b[16];
    #pragma unroll
    for (int i = 0; i < 16; ++i) {
        const size_t h = (size_t)(g * 16 + i);
        a[i] = ws[OFF_APROD + h * NPAIR + p];
        b[i] = ws[OFF_BACC  + h * NPAIR + p];
    }
    float Ag = a[0], Bg = b[0];
    #pragma unroll
    for (int i = 1; i < 16; ++i) { Bg = a[i] * Bg + b[i]; Ag = Ag * a[i]; }
    aggA[g][pl] = Ag;
    aggB[g][pl] = Bg;
    __syncthreads();
    {
        const int wv = t >> 6, lane = t & 63;
        float A2 = aggA[lane][wv];
        float B2 = aggB[lane][wv];
        #pragma unroll
        for (int off = 1; off < 64; off <<= 1) {
            const float pa = __shfl_up(A2, off);
            const float pb = __shfl_up(B2, off);
            if (lane >= off) { B2 = A2 * pb + B2; A2 = A2 * pa; }
        }
        float Pb = __shfl_up(B2, 1);
        if (lane == 0) Pb = 0.f;
        aggB[lane][wv] = Pb;
    }
    __syncthreads();
    float Pb = aggB[g][pl];
    #pragma unroll
    for (int i = 0; i < 16; ++i) {
        ws[OFF_CT + (size_t)(g * 16 + i) * NPAIR + p] = Pb;
        Pb = a[i] * Pb + b[i];
    }
}

__global__ __launch_bounds__(256, 4) void k45_apply_out(
    const void* __restrict__ A_log, const void* __restrict__ D_param,
    const void* __restrict__ ln_w, const void* __restrict__ out_proj_w,
    float* __restrict__ ws, void* __restrict__ out)
{
    __shared__ __align__(16) float sbm[DS][36];
    __shared__ __align__(16) float scm[DS][36];
    __shared__ __align__(16) float sy[DI][36];
    __shared__ float w_out_s[CD][DI];
    const int tid = threadIdx.x;
    const int hb  = blockIdx.x;
    const size_t t0 = (size_t)hb * LH;
    const bool isb = detect_bf16(ln_w);
    const __hip_bfloat16* sz_bf = (const __hip_bfloat16*)(ws + OFF_SZ);
    const __hip_bfloat16* xc_bf = (const __hip_bfloat16*)(ws + OFF_XC);

    if (isb) {
        const __hip_bfloat16* opw = (const __hip_bfloat16*)out_proj_w;
        for (int i = tid; i < CD * DI; i += 256) w_out_s[i >> 6][i & 63] = bf2f(opw[i]);
    } else {
        const float* opw = (const float*)out_proj_w;
        for (int i = tid; i < CD * DI; i += 256) w_out_s[i >> 6][i & 63] = opw[i];
    }
    {
        const int q = tid & 7, r = (tid >> 3) & 15;
        if (tid < 128) *(float4*)&sbm[r][q * 4] = *(const float4*)&ws[OFF_BM + (size_t)r * L + t0 + q * 4];
        else           *(float4*)&scm[r][q * 4] = *(const float4*)&ws[OFF_CM + (size_t)r * L + t0 + q * 4];
    }
    const int d = tid >> 2, sg = tid & 3;
    float Aj[4];
    #pragma unroll
    for (int j = 0; j < 4; ++j) Aj[j] = -__expf(ldin(A_log, d * DS + sg + 4 * j, isb));
    const float Dd = ldin(D_param, d, isb);
    const float4 h4 = *(const float4*)&ws[OFF_CT + (size_t)hb * NPAIR + tid * 4];
    float hh[4]; f4arr(h4, hh);
    __syncthreads();

    const float* dlp = ws + OFF_DELTA + (size_t)d * L + t0;
    const __hip_bfloat16* xcp = xc_bf + (size_t)d * L + t0;
    for (int t = 0; t < LH; t += 4) {
        float ddv[4], xxv[4], bm[4][4], cm[4][4];
        f4arr(*(const float4*)(dlp + t), ddv);
        const ushort4 xq = *(const ushort4*)(xcp + t);
        xxv[0] = bfu(xq.x); xxv[1] = bfu(xq.y); xxv[2] = bfu(xq.z); xxv[3] = bfu(xq.w);
        f4arr(*(const float4*)&sbm[sg][t],      bm[0]);
        f4arr(*(const float4*)&sbm[sg + 4][t],  bm[1]);
        f4arr(*(const float4*)&sbm[sg + 8][t],  bm[2]);
        f4arr(*(const float4*)&sbm[sg + 12][t], bm[3]);
        f4arr(*(const float4*)&scm[sg][t],      cm[0]);
        f4arr(*(const float4*)&scm[sg + 4][t],  cm[1]);
        f4arr(*(const float4*)&scm[sg + 8][t],  cm[2]);
        f4arr(*(const float4*)&scm[sg + 12][t], cm[3]);
        #pragma unroll
        for (int tt = 0; tt < 4; ++tt) {
            const float dxc = ddv[tt] * xxv[tt];
            float ys = 0.f;
            #pragma unroll
            for (int j = 0; j < 4; ++j) {
                const float e = __expf(ddv[tt] * Aj[j]);
                hh[j] = e * hh[j] + dxc * bm[j][tt];
                ys += hh[j] * cm[j][tt];
            }
            ys += __shfl_xor(ys, 1);
            ys += __shfl_xor(ys, 2);
            if (sg == 0) sy[d][t + tt] = ys + xxv[tt] * Dd;
        }
    }
    __syncthreads();
    #pragma unroll
    for (int k = 0; k < 2; ++k) {
        const int idx = tid + k * 256;
        const int r = idx >> 3, c4 = (idx & 7) * 4;
        float4 yv = *(float4*)&sy[r][c4];
        const ushort4 zq = *(const ushort4*)(sz_bf + (size_t)r * L + t0 + c4);
        yv.x *= bfu(zq.x); yv.y *= bfu(zq.y); yv.z *= bfu(zq.z); yv.w *= bfu(zq.w);
        *(float4*)&sy[r][c4] = yv;
    }
    __syncthreads();
    {
        const int g   = tid >> 5;
        const int pos = tid & 31;
        float acc[4] = {0.f, 0.f, 0.f, 0.f};
        for (int dd2 = 0; dd2 < DI; ++dd2) {
            const float yv = sy[dd2][pos];
            #pragma unroll
            for (int j = 0; j < 4; ++j)
                acc[j] += yv * w_out_s[g * 4 + j][dd2];
        }
        const size_t l = t0 + pos;
        #pragma unroll
        for (int j = 0; j < 4; ++j) {
            const int cc = g * 4 + j;
            if (isb) ((__hip_bfloat16*)out)[(size_t)cc * L + l] = __float2bfloat16(acc[j]);
            else     ((float*)out)[(size_t)cc * L + l] = acc[j];
        }
    }
}

extern "C" void kernel_launch(void* const* d_in, const int* in_sizes, int n_in,
                              void* d_out, int out_size, void* d_ws, size_t ws_size,
                              hipStream_t stream)
{
    (void)in_sizes; (void)n_in; (void)out_size; (void)ws_size;
    const void* x        = d_in[0];
    const void* ln_w     = d_in[1];
    const void* ln_b     = d_in[2];
    const void* in_pw    = d_in[3];
    const void* conv_w   = d_in[4];
    const void* conv_b   = d_in[5];
    const void* x_pw     = d_in[6];
    const void* dt_pw    = d_in[7];
    const void* dt_pb    = d_in[8];
    const void* A_log    = d_in[9];
    const void* D_param  = d_in[10];
    const void* out_pw   = d_in[11];
    float* ws = (float*)d_ws;

    void* args[] = {
        (void*)&x, (void*)&ln_w, (void*)&ln_b, (void*)&in_pw,
        (void*)&conv_w, (void*)&conv_b, (void*)&x_pw,
        (void*)&dt_pw, (void*)&dt_pb, (void*)&A_log,
        (void*)&D_param, (void*)&out_pw, (void*)&ws, (void*)&d_out
    };
    hipError_t err = hipLaunchCooperativeKernel((void*)fused_umamba, dim3(NCH),
                                                dim3(256), args, 0, stream);
    if (err != hipSuccess) {
        // deterministic fallback: known-passing 3-kernel pipeline
        k12_featurize_scan<<<NCH, 256, 0, stream>>>(x, ln_w, ln_b, in_pw, conv_w,
                                                    conv_b, x_pw, dt_pw, dt_pb,
                                                    A_log, ws);
        k3_carry<<<NPAIR / 16, 1024, 0, stream>>>(ws);
        k45_apply_out<<<NHC, 256, 0, stream>>>(A_log, D_param, ln_w, out_pw, ws, d_out);
    }
}